// Round 4
// baseline (284.755 us; speedup 1.0000x reference)
//
#include <hip/hip_runtime.h>

#define NCLS   100000
#define FEAT   192
#define F4     48
#define TILE   64
#define NB     512
#define NT     ((NCLS + TILE - 1)/TILE)   // 1563
#define GMAX   (NCLS*F4 - 1)              // 4799999

// workspace layout (float offsets)
#define XN_OFF   0
#define CM_OFF   6144
#define SM_OFF   6176
#define TH_OFF   6208
#define MM_OFF   6240
#define RG_OFF   6272
#define LV_OFF   6304
#define TGT_OFF  6336
#define CMAT_OFF 7360
#define PART_OFF 8384

#define L2E30 43.2808512266689f
#define LN2   0.69314718055994531f

__device__ __forceinline__ float dot4(float4 a, float4 b){
  return fmaf(a.x,b.x, fmaf(a.y,b.y, fmaf(a.z,b.z, a.w*b.w)));
}
__device__ __forceinline__ void fma4(float4& a, float4 x, float4 w){
  a.x = fmaf(x.x,w.x,a.x); a.y = fmaf(x.y,w.y,a.y);
  a.z = fmaf(x.z,w.z,a.z); a.w = fmaf(x.w,w.w,a.w);
}
__device__ __forceinline__ float hsum4(float4 v){ return (v.x+v.y)+(v.z+v.w); }

// ---------------- K1: prep (xn, per-m params, lv, tgt) — unchanged ----------------
__global__ __launch_bounds__(256) void k1_prep(const float* __restrict__ pe,
                                               const int* __restrict__ gt,
                                               const float* __restrict__ wgt,
                                               float* __restrict__ ws)
{
  __shared__ float4 PE4[1536];
  __shared__ float INVN[32], CML[32], SML[32], THL[32], MML[32];
  const int tid = threadIdx.x;
  const float4* pe4 = (const float4*)pe;
  for (int i = tid; i < 1536; i += 256) PE4[i] = pe4[i];
  __syncthreads();

  const int m   = tid >> 3;
  const int sub = tid & 7;
  float ssq = 0.f;
  for (int j = 0; j < 6; ++j){ float4 v = PE4[m*F4 + sub + 8*j]; ssq += dot4(v,v); }
  ssq += __shfl_xor(ssq,1); ssq += __shfl_xor(ssq,2); ssq += __shfl_xor(ssq,4);
  float nrm = sqrtf(ssq);
  if (sub == 0){
    INVN[m] = 1.f / fmaxf(nrm, 1e-12f);
    float nc = fminf(fmaxf(nrm, 10.f), 110.f);
    float mi = fmaf(0.01f, nc, 100.f/nc);
    const float pi = 3.14159265358979323846f;
    float cmv = cosf(mi), smv = sinf(mi);
    float thv = cosf(pi - mi);
    float mmv = sinf(pi - mi)*mi;
    CML[m]=cmv; SML[m]=smv; THL[m]=thv; MML[m]=mmv;
    ws[CM_OFF+m]=cmv; ws[SM_OFF+m]=smv; ws[TH_OFF+m]=thv; ws[MM_OFF+m]=mmv;
    float dr = nc - 60.f;
    ws[RG_OFF+m] = 0.07f*dr*dr;
  }
  if (tid < 32) ws[LV_OFF+tid] = (float)gt[tid];
  __syncthreads();

  float* PEf = (float*)PE4;
  for (int i = tid; i < 6144; i += 256){
    float v = PEf[i] * INVN[i/FEAT];
    PEf[i] = v;
    ws[XN_OFF+i] = v;
  }
  __syncthreads();

  const int s  = tid >> 3;
  const int cs = gt[s];
  const float4* gw4 = (const float4*)wgt;
  float4 wreg[6];
  float wsq = 0.f;
  for (int j = 0; j < 6; ++j){
    wreg[j] = gw4[(long)cs*F4 + sub + 8*j];
    wsq += dot4(wreg[j], wreg[j]);
  }
  wsq += __shfl_xor(wsq,1); wsq += __shfl_xor(wsq,2); wsq += __shfl_xor(wsq,4);
  float invw = 1.f / fmaxf(sqrtf(wsq), 1e-12f);
  float lvv = (float)cs;
  for (int mm2 = 0; mm2 < 32; ++mm2){
    float dp = 0.f;
    for (int j = 0; j < 6; ++j) dp += dot4(PE4[mm2*F4 + sub + 8*j], wreg[j]);
    dp += __shfl_xor(dp,1); dp += __shfl_xor(dp,2); dp += __shfl_xor(dp,4);
    if (sub == 0){
      float c = dp * invw;
      float sine = sqrtf(fminf(fmaxf(1.f - c*c, 0.f), 1.f));
      float phi = c*CML[mm2] - sine*SML[mm2];
      phi = (c > THL[mm2]) ? phi : (c - MML[mm2]);
      ws[TGT_OFF + s*32 + mm2] = fmaf(30.f*lvv, phi - c, 30.f*c);
    }
  }
}

// ---------------- K2: wave-per-m-group fused GEMM + online logsumexp ----------------
// lane <-> class (64/tile), wave w <-> m in [8w, 8w+8). xn via wave-uniform (scalar) loads.
// W tile XOR-16 swizzled in LDS (row stride 768B is a full bank collision unswizzled).
// Register prefetch of tile t+1 during tile t's dot phase; 2 barriers per tile.
__global__ __launch_bounds__(256, 2) void k2_main(const float* __restrict__ wgt,
                                                  const float* __restrict__ wsr,
                                                  float2* __restrict__ part)
{
  __shared__ float4 W4[TILE*F4];   // 48KB, slot (cls, j') holds global col j'^(cls&15)
  __shared__ float4 OBS[TILE*8];   // 8KB, group slot g' = g ^ (cls&7)
  __shared__ float4 OSS[TILE*8];   // 8KB
  __shared__ float  NRM[TILE];
  __shared__ float  LVS[32];

  const int tid  = threadIdx.x;
  const int lane = tid & 63;
  const int wv   = tid >> 6;       // wave id = m-group
  const int m0   = wv*8;
  const float4* gw4 = (const float4*)wgt;
  const float4* xn4 = (const float4*)(wsr + XN_OFF);

  if (tid < 32) LVS[tid] = wsr[LV_OFF + tid];

  float cmv[8], smv[8], thw[8], mmw[8];
#pragma unroll
  for (int q = 0; q < 8; ++q){
    cmv[q] = wsr[CM_OFF + m0 + q]; smv[q] = wsr[SM_OFF + m0 + q];
    thw[q] = wsr[TH_OFF + m0 + q]; mmw[q] = wsr[MM_OFF + m0 + q];
  }

  const int s_acc = tid & 31;      // accumulate role: s
  const int mgr   = tid >> 5;      // accumulate role: m-f4-group 0..7
  float mx[4], sums[4];
#pragma unroll
  for (int qi = 0; qi < 4; ++qi){ mx[qi] = -1e30f; sums[qi] = 0.f; }

  // prologue: stage first tile
  int t = blockIdx.x;
  float4 pre[12];
#pragma unroll
  for (int r = 0; r < 12; ++r){
    int gi = t*(TILE*F4) + tid + 256*r; if (gi > GMAX) gi = GMAX;
    pre[r] = gw4[gi];
  }
#pragma unroll
  for (int r = 0; r < 12; ++r){
    int si = tid + 256*r;
    int cls = si/F4, j = si - cls*F4;
    W4[cls*F4 + (j ^ (cls & 15))] = pre[r];
  }
  __syncthreads();
  const float lvs = LVS[s_acc];
  const int swz = lane & 15;
  const int k7r = mgr;             // reader group index

  for (; t < NT; t += NB){
    const int tn = t + NB;
    const bool hasNext = (tn < NT);
    if (hasNext){
#pragma unroll
      for (int r = 0; r < 12; ++r){
        int gi = tn*(TILE*F4) + tid + 256*r; if (gi > GMAX) gi = GMAX;
        pre[r] = gw4[gi];
      }
    }
    // ---- dot phase: acc[q] = sum_k xn[m0+q][k]*W[lane][k]; wave0 also accumulates |W|^2
    float4 acc[8]; float4 nsq = make_float4(0,0,0,0);
#pragma unroll
    for (int q = 0; q < 8; ++q) acc[q] = make_float4(0,0,0,0);
#pragma unroll 4
    for (int k4 = 0; k4 < F4; ++k4){
      float4 w = W4[lane*F4 + (k4 ^ swz)];
      if (wv == 0) fma4(nsq, w, w);
#pragma unroll
      for (int q = 0; q < 8; ++q){
        int xi = __builtin_amdgcn_readfirstlane((m0 + q)*F4 + k4);
        float4 xv = xn4[xi];
        fma4(acc[q], xv, w);
      }
    }
    if (wv == 0) NRM[lane] = rsqrtf(fmaxf(hsum4(nsq), 1e-24f));
    __syncthreads();                      // barrier1: W reads done, NRM visible
    if (hasNext){                         // write next tile (vmcnt wait auto-inserted)
#pragma unroll
      for (int r = 0; r < 12; ++r){
        int si = tid + 256*r;
        int cls = si/F4, j = si - cls*F4;
        W4[cls*F4 + (j ^ (cls & 15))] = pre[r];
      }
    }
    // ---- transform: cosine -> (ob, os) in log2 domain; write to OBS/OSS
    {
      float invn = NRM[lane];
      float4 obv[2], osv[2];
#pragma unroll
      for (int q = 0; q < 8; ++q){
        float c = hsum4(acc[q]) * invn;
        float sine = sqrtf(fminf(fmaxf(1.f - c*c, 0.f), 1.f));
        float phi = c*cmv[q] - sine*smv[q];
        phi = (c > thw[q]) ? phi : (c - mmw[q]);
        ((float*)&obv[q>>2])[q&3] = L2E30 * c;
        ((float*)&osv[q>>2])[q&3] = L2E30 * (phi - c);
      }
      const int k7 = lane & 7;
      OBS[lane*8 + ((2*wv)   ^ k7)] = obv[0];
      OBS[lane*8 + ((2*wv+1) ^ k7)] = obv[1];
      OSS[lane*8 + ((2*wv)   ^ k7)] = osv[0];
      OSS[lane*8 + ((2*wv+1) ^ k7)] = osv[1];
    }
    __syncthreads();                      // barrier2: OBS/OSS visible, W(t+1) visible
    // ---- accumulate: online lse over this tile's classes (broadcast LDS reads)
    const int nv = (NCLS - t*TILE < TILE) ? (NCLS - t*TILE) : TILE;
    for (int ci = 0; ci < nv; ++ci){
      int slot = ci*8 + (k7r ^ (ci & 7));
      float4 ob = OBS[slot];
      float4 os = OSS[slot];
      float ov[4] = { fmaf(lvs, os.x, ob.x), fmaf(lvs, os.y, ob.y),
                      fmaf(lvs, os.z, ob.z), fmaf(lvs, os.w, ob.w) };
#pragma unroll
      for (int qi = 0; qi < 4; ++qi){
        float d2 = ov[qi] - mx[qi];
        if (d2 > 0.f){ sums[qi] = fmaf(sums[qi], exp2f(-d2), 1.f); mx[qi] = ov[qi]; }
        else if (d2 > -28.f) sums[qi] += exp2f(d2);
      }
    }
    // no barrier3: next iteration's barrier1 protects OBS/OSS
  }
#pragma unroll
  for (int qi = 0; qi < 4; ++qi){
    int pp = s_acc*32 + 4*mgr + qi;
    part[(long)pp*NB + blockIdx.x] = make_float2(mx[qi], sums[qi]);
  }
}

// ---------------- K3: combine partials -> cost matrix (unchanged) ----------------
__global__ __launch_bounds__(64) void k3_reduce(const float2* part, float* ws)
{
  const int p = blockIdx.x;
  const int l = threadIdx.x;
  float M = -1e30f, S = 0.f;
  for (int r = 0; r < NB/64; ++r){
    float2 v = part[(long)p*NB + l + 64*r];
    float M2 = fmaxf(M, v.x);
    S = S*exp2f(M - M2) + v.y*exp2f(v.x - M2);
    M = M2;
  }
  for (int k = 1; k < 64; k <<= 1){
    float Mo = __shfl_xor(M, k);
    float So = __shfl_xor(S, k);
    float M2 = fmaxf(M, Mo);
    S = S*exp2f(M - M2) + So*exp2f(Mo - M2);
    M = M2;
  }
  if (l == 0){
    float lse = LN2*(M + log2f(S));
    ws[CMAT_OFF + p] = lse - ws[TGT_OFF + p] + ws[RG_OFF + (p & 31)];
  }
}

// ---------------- K4: Hungarian with DPP min-reduce + readlane scalar chases ----------------
__device__ __forceinline__ float wave_min64(float x){
  float r = x;
#define DPPSTEP(ctrl) { int t_ = __builtin_amdgcn_update_dpp(__float_as_int(r), __float_as_int(r), (ctrl), 0xf, 0xf, false); r = fminf(r, __int_as_float(t_)); }
  DPPSTEP(0x111)  // row_shr:1
  DPPSTEP(0x112)  // row_shr:2
  DPPSTEP(0x114)  // row_shr:4
  DPPSTEP(0x118)  // row_shr:8
  DPPSTEP(0x142)  // row_bcast:15
  DPPSTEP(0x143)  // row_bcast:31
#undef DPPSTEP
  return __int_as_float(__builtin_amdgcn_readlane(__float_as_int(r), 63));
}

__global__ __launch_bounds__(64) void k4_final(const float* __restrict__ psin,
                                               const float* __restrict__ wsr,
                                               float* __restrict__ out)
{
  __shared__ float CL[1024];
  const int l = threadIdx.x;
  for (int i = l; i < 1024; i += 64) CL[i] = wsr[CMAT_OFF + i];
  __syncthreads();

  float v = 0.f, uu = 0.f;     // v[j], u[p[j]] for lane's column j = l+1
  int p = 0, way = 0;
  for (int i = 1; i <= 32; ++i){
    float minv = 1e30f;
    int used = (l < 32) ? 0 : 1;
    way = 0;
    float uu0 = 0.f;
    int j0 = 0;
    for (int guard = 0; guard < 64; ++guard){
      if (j0 > 0 && l == j0-1) used = 1;
      int i0; float u0;
      if (j0 == 0){ i0 = i; u0 = uu0; }
      else {
        i0 = __builtin_amdgcn_readlane(p, j0-1);
        u0 = __int_as_float(__builtin_amdgcn_readlane(__float_as_int(uu), j0-1));
      }
      float cst = CL[(i0-1)*32 + (l & 31)];
      float cur = cst - u0 - v;
      if (!used && cur < minv){ minv = cur; way = j0; }
      float mval = used ? 1e30f : minv;
      float dmin = wave_min64(mval);
      unsigned long long b = __ballot(mval == dmin);
      int j1 = __builtin_ctzll(b) + 1;     // lowest j argmin = reference tie-break
      if (used){ uu += dmin; v -= dmin; } else { minv -= dmin; }
      uu0 += dmin;
      int pn = __builtin_amdgcn_readlane(p, j1-1);
      j0 = j1;
      if (pn == 0) break;
    }
    for (int guard = 0; guard < 40 && j0 != 0; ++guard){
      int jw = __builtin_amdgcn_readlane(way, j0-1);
      int pp_; float pu;
      if (jw == 0){ pp_ = i; pu = uu0; }
      else {
        pp_ = __builtin_amdgcn_readlane(p, jw-1);
        pu = __int_as_float(__builtin_amdgcn_readlane(__float_as_int(uu), jw-1));
      }
      if (l == j0-1){ p = pp_; uu = pu; }
      j0 = jw;
    }
  }
  float csum = 0.f;
  if (l < 32) csum = CL[(p-1)*32 + l];
  for (int k = 1; k < 64; k <<= 1) csum += __shfl_xor(csum, k);
  float lex = 0.f;
  if (l < 32){
    float pv = psin[l];
    pv = fminf(fmaxf(pv, 1e-6f), 1.f - 1e-6f);
    lex = -logf(pv);
  }
  for (int k = 1; k < 64; k <<= 1) lex += __shfl_xor(lex, k);
  if (l == 0)
    out[0] = csum/32.f + 100.f*(lex/32.f) + 100.f*LN2;
}

extern "C" void kernel_launch(void* const* d_in, const int* in_sizes, int n_in,
                              void* d_out, int out_size, void* d_ws, size_t ws_size,
                              hipStream_t stream)
{
  (void)in_sizes; (void)n_in; (void)out_size; (void)ws_size;
  const float* pe  = (const float*)d_in[0];
  const float* ps  = (const float*)d_in[1];
  const int*   gt  = (const int*)  d_in[2];
  const float* wgt = (const float*)d_in[3];
  float* ws  = (float*)d_ws;
  float* out = (float*)d_out;
  hipLaunchKernelGGL(k1_prep,   dim3(1),    dim3(256), 0, stream, pe, gt, wgt, ws);
  hipLaunchKernelGGL(k2_main,   dim3(NB),   dim3(256), 0, stream, wgt, ws,
                     (float2*)(ws + PART_OFF));
  hipLaunchKernelGGL(k3_reduce, dim3(1024), dim3(64),  0, stream,
                     (const float2*)(ws + PART_OFF), ws);
  hipLaunchKernelGGL(k4_final,  dim3(1),    dim3(64),  0, stream, ps, ws, out);
}

// Round 5
// 246.798 us; speedup vs baseline: 1.1538x; 1.1538x over previous
//
#include <hip/hip_runtime.h>

#define NCLS   100000
#define FEAT   192
#define F4     48
#define TILE   64
#define TSZ    (TILE*F4)                  // 3072 float4 per tile
#define NB     512
#define NT     ((NCLS + TILE - 1)/TILE)   // 1563
#define GMAX   (NCLS*F4 - 1)

// workspace layout (float offsets)
#define XN_OFF   0
#define CM_OFF   6144
#define SM_OFF   6176
#define TH_OFF   6208
#define MM_OFF   6240
#define RG_OFF   6272
#define LV_OFF   6304
#define TGT_OFF  6336      // tgt2[s][m], log2-domain (written by k2 hit-path)
#define CMAT_OFF 7360
#define PART_OFF 8384

#define L2E30 43.2808512266689f
#define LN2   0.69314718055994531f

__device__ __forceinline__ float dot4(float4 a, float4 b){
  return fmaf(a.x,b.x, fmaf(a.y,b.y, fmaf(a.z,b.z, a.w*b.w)));
}
__device__ __forceinline__ void fma4(float4& a, float4 x, float4 w){
  a.x = fmaf(x.x,w.x,a.x); a.y = fmaf(x.y,w.y,a.y);
  a.z = fmaf(x.z,w.z,a.z); a.w = fmaf(x.w,w.w,a.w);
}
__device__ __forceinline__ float hsum4(float4 v){ return (v.x+v.y)+(v.z+v.w); }

// ---------------- K1: prep (xn, per-m params, lv) — tgt moved to k2 ----------------
__global__ __launch_bounds__(256) void k1_prep(const float* __restrict__ pe,
                                               const int* __restrict__ gt,
                                               float* __restrict__ ws)
{
  __shared__ float4 PE4[1536];
  __shared__ float INVN[32];
  const int tid = threadIdx.x;
  const float4* pe4 = (const float4*)pe;
  for (int i = tid; i < 1536; i += 256) PE4[i] = pe4[i];
  __syncthreads();

  const int m   = tid >> 3;
  const int sub = tid & 7;
  float ssq = 0.f;
  for (int j = 0; j < 6; ++j){ float4 v = PE4[m*F4 + sub + 8*j]; ssq += dot4(v,v); }
  ssq += __shfl_xor(ssq,1); ssq += __shfl_xor(ssq,2); ssq += __shfl_xor(ssq,4);
  float nrm = sqrtf(ssq);
  if (sub == 0){
    INVN[m] = 1.f / fmaxf(nrm, 1e-12f);
    float nc = fminf(fmaxf(nrm, 10.f), 110.f);
    float mi = fmaf(0.01f, nc, 100.f/nc);
    const float pi = 3.14159265358979323846f;
    ws[CM_OFF+m] = cosf(mi);
    ws[SM_OFF+m] = sinf(mi);
    ws[TH_OFF+m] = cosf(pi - mi);
    ws[MM_OFF+m] = sinf(pi - mi)*mi;
    float dr = nc - 60.f;
    ws[RG_OFF+m] = 0.07f*dr*dr;              // GAMMA*LMBDA*0.01 = 0.07
  }
  if (tid < 32) ws[LV_OFF+tid] = (float)gt[tid];
  __syncthreads();

  for (int i = tid; i < 6144; i += 256)
    ws[XN_OFF+i] = ((float*)PE4)[i] * INVN[i/FEAT];
}

// ---------------- K2: fused GEMM + online logsumexp ----------------
// lane <-> class (64/tile), wave w <-> m-group [8w, 8w+8). xn via scalar loads.
// W staged by global_load_lds: LDS linear, source pre-swizzled (j ^= cls&15).
// Async prefetch of tile t+1 issued after bar2; accumulate phase hides latency.
__global__ __launch_bounds__(256, 2) void k2_main(const float* __restrict__ wgt,
                                                  const float* __restrict__ wsr,
                                                  const int* __restrict__ gt,
                                                  float2* __restrict__ part,
                                                  float* __restrict__ wsw)
{
  __shared__ float4 W4[TSZ];       // 48KB linear; slot (cls,j') holds global col j'^(cls&15)
  __shared__ float4 OBS[TILE*8];   // 8KB
  __shared__ float4 OSS[TILE*8];   // 8KB
  __shared__ float  NRM[TILE];

  const int tid  = threadIdx.x;
  const int lane = tid & 63;
  const int wv   = tid >> 6;
  const int m0   = __builtin_amdgcn_readfirstlane(wv*8);
  const float4* gw4 = (const float4*)wgt;
  const float4* xn4 = (const float4*)(wsr + XN_OFF);

  // per-thread pre-swizzled source offsets for the 12 staging rounds
  int off_r[12];
#pragma unroll
  for (int r = 0; r < 12; ++r){
    int si  = (wv*12 + r)*64 + lane;
    int cls = si / F4;
    int jp  = si - cls*F4;
    off_r[r] = cls*F4 + (jp ^ (cls & 15));
  }

  float cmv[8], smv[8], thw[8], mmw[8];   // wave-uniform -> SGPRs
#pragma unroll
  for (int q = 0; q < 8; ++q){
    cmv[q] = wsr[CM_OFF+m0+q]; smv[q] = wsr[SM_OFF+m0+q];
    thw[q] = wsr[TH_OFF+m0+q]; mmw[q] = wsr[MM_OFF+m0+q];
  }

  const int s_acc = tid & 31;
  const int mgr   = tid >> 5;
  const int gt_s  = gt[s_acc];
  const float lvs = (float)gt_s;
  float mx[4], sums[4];
#pragma unroll
  for (int qi = 0; qi < 4; ++qi){ mx[qi] = -1e30f; sums[qi] = 0.f; }

  // async stage of tile tt into W4 (12 x global_load_lds, 16B/lane, zero VGPR cost)
  auto stage = [&](int tt){
#pragma unroll
    for (int r = 0; r < 12; ++r){
      int gi = tt*TSZ + off_r[r];
      if (gi > GMAX) gi = GMAX;
      __builtin_amdgcn_global_load_lds(
          (const __attribute__((address_space(1))) void*)(gw4 + gi),
          (__attribute__((address_space(3))) void*)(W4 + (wv*12 + r)*64),
          16, 0, 0);
    }
  };

  int t = blockIdx.x;
  stage(t);
  __syncthreads();                       // vmcnt(0) drain -> W4(t) ready

  const int swz = lane & 15;
  for (; t < NT; t += NB){
    // ---- dot: acc[q] = sum_k xn[m0+q][k]*W[lane][k]; wave0 accumulates |W|^2
    float4 acc[8]; float4 nsq = make_float4(0,0,0,0);
#pragma unroll
    for (int q = 0; q < 8; ++q) acc[q] = make_float4(0,0,0,0);
#pragma unroll 4
    for (int k4 = 0; k4 < F4; ++k4){
      float4 w = W4[lane*F4 + (k4 ^ swz)];
      if (wv == 0) fma4(nsq, w, w);
#pragma unroll
      for (int q = 0; q < 8; ++q){
        int xi = __builtin_amdgcn_readfirstlane((m0 + q)*F4 + k4);
        float4 xv = xn4[xi];
        fma4(acc[q], xv, w);
      }
    }
    if (wv == 0) NRM[lane] = rsqrtf(fmaxf(hsum4(nsq), 1e-24f));
    __syncthreads();                     // bar1: W reads done, NRM visible
    // ---- transform: cosine -> (ob, os) in log2 domain
    {
      float invn = NRM[lane];
      float4 obv[2], osv[2];
#pragma unroll
      for (int q = 0; q < 8; ++q){
        float c = hsum4(acc[q]) * invn;
        float sine = sqrtf(fminf(fmaxf(1.f - c*c, 0.f), 1.f));
        float phi = c*cmv[q] - sine*smv[q];
        phi = (c > thw[q]) ? phi : (c - mmw[q]);
        ((float*)&obv[q>>2])[q&3] = L2E30 * c;
        ((float*)&osv[q>>2])[q&3] = L2E30 * (phi - c);
      }
      const int k7 = lane & 7;
      OBS[lane*8 + ((2*wv)   ^ k7)] = obv[0];
      OBS[lane*8 + ((2*wv+1) ^ k7)] = obv[1];
      OSS[lane*8 + ((2*wv)   ^ k7)] = osv[0];
      OSS[lane*8 + ((2*wv+1) ^ k7)] = osv[1];
    }
    __syncthreads();                     // bar2: OBS/OSS visible (no vmem outstanding)
    if (t + NB < NT) stage(t + NB);      // async prefetch; hidden under accumulate
    const int nv = (NCLS - t*TILE < TILE) ? (NCLS - t*TILE) : TILE;
    // ---- rare tgt-hit: record tgt2[s][m] from the same ob/os values
    {
      int rel = gt_s - t*TILE;
      if ((unsigned)rel < (unsigned)nv){
        int slot = rel*8 + (mgr ^ (rel & 7));
        float4 ob = OBS[slot];
        float4 os = OSS[slot];
        wsw[TGT_OFF + s_acc*32 + 4*mgr + 0] = fmaf(lvs, os.x, ob.x);
        wsw[TGT_OFF + s_acc*32 + 4*mgr + 1] = fmaf(lvs, os.y, ob.y);
        wsw[TGT_OFF + s_acc*32 + 4*mgr + 2] = fmaf(lvs, os.z, ob.z);
        wsw[TGT_OFF + s_acc*32 + 4*mgr + 3] = fmaf(lvs, os.w, ob.w);
      }
    }
    // ---- accumulate: online lse over this tile's classes
    for (int ci = 0; ci < nv; ++ci){
      int slot = ci*8 + (mgr ^ (ci & 7));
      float4 ob = OBS[slot];
      float4 os = OSS[slot];
      float ov[4] = { fmaf(lvs, os.x, ob.x), fmaf(lvs, os.y, ob.y),
                      fmaf(lvs, os.z, ob.z), fmaf(lvs, os.w, ob.w) };
#pragma unroll
      for (int qi = 0; qi < 4; ++qi){
        float d2 = ov[qi] - mx[qi];
        if (d2 > 0.f){ sums[qi] = fmaf(sums[qi], exp2f(-d2), 1.f); mx[qi] = ov[qi]; }
        else if (d2 > -28.f) sums[qi] += exp2f(d2);
      }
    }
    __syncthreads();                     // bar3: drains prefetch vmcnt; W4(t+1) ready
  }
#pragma unroll
  for (int qi = 0; qi < 4; ++qi){
    int pp = s_acc*32 + 4*mgr + qi;
    part[(long)pp*NB + blockIdx.x] = make_float2(mx[qi], sums[qi]);
  }
}

// ---------------- K3: combine partials -> cost matrix ----------------
__global__ __launch_bounds__(64) void k3_reduce(const float2* part, float* ws)
{
  const int p = blockIdx.x;
  const int l = threadIdx.x;
  float M = -1e30f, S = 0.f;
  for (int r = 0; r < NB/64; ++r){
    float2 v = part[(long)p*NB + l + 64*r];
    float M2 = fmaxf(M, v.x);
    S = S*exp2f(M - M2) + v.y*exp2f(v.x - M2);
    M = M2;
  }
  for (int k = 1; k < 64; k <<= 1){
    float Mo = __shfl_xor(M, k);
    float So = __shfl_xor(S, k);
    float M2 = fmaxf(M, Mo);
    S = S*exp2f(M - M2) + So*exp2f(Mo - M2);
    M = M2;
  }
  if (l == 0){
    float lse2 = M + log2f(S);
    ws[CMAT_OFF + p] = LN2*(lse2 - ws[TGT_OFF + p]) + ws[RG_OFF + (p & 31)];
  }
}

// ---------------- K4: Hungarian (DPP min-reduce + readlane chases) ----------------
__device__ __forceinline__ float wave_min64(float x){
  float r = x;
#define DPPSTEP(ctrl) { int t_ = __builtin_amdgcn_update_dpp(__float_as_int(r), __float_as_int(r), (ctrl), 0xf, 0xf, false); r = fminf(r, __int_as_float(t_)); }
  DPPSTEP(0x111)
  DPPSTEP(0x112)
  DPPSTEP(0x114)
  DPPSTEP(0x118)
  DPPSTEP(0x142)
  DPPSTEP(0x143)
#undef DPPSTEP
  return __int_as_float(__builtin_amdgcn_readlane(__float_as_int(r), 63));
}

__global__ __launch_bounds__(64) void k4_final(const float* __restrict__ psin,
                                               const float* __restrict__ wsr,
                                               float* __restrict__ out)
{
  __shared__ float CL[1024];
  const int l = threadIdx.x;
  for (int i = l; i < 1024; i += 64) CL[i] = wsr[CMAT_OFF + i];
  __syncthreads();

  float v = 0.f, uu = 0.f;
  int p = 0, way = 0;
  for (int i = 1; i <= 32; ++i){
    float minv = 1e30f;
    int used = (l < 32) ? 0 : 1;
    way = 0;
    float uu0 = 0.f;
    int j0 = 0;
    for (int guard = 0; guard < 64; ++guard){
      if (j0 > 0 && l == j0-1) used = 1;
      int i0; float u0;
      if (j0 == 0){ i0 = i; u0 = uu0; }
      else {
        i0 = __builtin_amdgcn_readlane(p, j0-1);
        u0 = __int_as_float(__builtin_amdgcn_readlane(__float_as_int(uu), j0-1));
      }
      float cst = CL[(i0-1)*32 + (l & 31)];
      float cur = cst - u0 - v;
      if (!used && cur < minv){ minv = cur; way = j0; }
      float mval = used ? 1e30f : minv;
      float dmin = wave_min64(mval);
      unsigned long long b = __ballot(mval == dmin);
      int j1 = __builtin_ctzll(b) + 1;
      if (used){ uu += dmin; v -= dmin; } else { minv -= dmin; }
      uu0 += dmin;
      int pn = __builtin_amdgcn_readlane(p, j1-1);
      j0 = j1;
      if (pn == 0) break;
    }
    for (int guard = 0; guard < 40 && j0 != 0; ++guard){
      int jw = __builtin_amdgcn_readlane(way, j0-1);
      int pp_; float pu;
      if (jw == 0){ pp_ = i; pu = uu0; }
      else {
        pp_ = __builtin_amdgcn_readlane(p, jw-1);
        pu = __int_as_float(__builtin_amdgcn_readlane(__float_as_int(uu), jw-1));
      }
      if (l == j0-1){ p = pp_; uu = pu; }
      j0 = jw;
    }
  }
  float csum = 0.f;
  if (l < 32) csum = CL[(p-1)*32 + l];
  for (int k = 1; k < 64; k <<= 1) csum += __shfl_xor(csum, k);
  float lex = 0.f;
  if (l < 32){
    float pv = psin[l];
    pv = fminf(fmaxf(pv, 1e-6f), 1.f - 1e-6f);
    lex = -logf(pv);
  }
  for (int k = 1; k < 64; k <<= 1) lex += __shfl_xor(lex, k);
  if (l == 0)
    out[0] = csum/32.f + 100.f*(lex/32.f) + 100.f*LN2;
}

extern "C" void kernel_launch(void* const* d_in, const int* in_sizes, int n_in,
                              void* d_out, int out_size, void* d_ws, size_t ws_size,
                              hipStream_t stream)
{
  (void)in_sizes; (void)n_in; (void)out_size; (void)ws_size;
  const float* pe  = (const float*)d_in[0];
  const float* ps  = (const float*)d_in[1];
  const int*   gt  = (const int*)  d_in[2];
  const float* wgt = (const float*)d_in[3];
  float* ws  = (float*)d_ws;
  float* out = (float*)d_out;
  hipLaunchKernelGGL(k1_prep,   dim3(1),    dim3(256), 0, stream, pe, gt, ws);
  hipLaunchKernelGGL(k2_main,   dim3(NB),   dim3(256), 0, stream, wgt, ws, gt,
                     (float2*)(ws + PART_OFF), ws);
  hipLaunchKernelGGL(k3_reduce, dim3(1024), dim3(64),  0, stream,
                     (const float2*)(ws + PART_OFF), ws);
  hipLaunchKernelGGL(k4_final,  dim3(1),    dim3(64),  0, stream, ps, ws, out);
}

// Round 6
// 182.378 us; speedup vs baseline: 1.5613x; 1.3532x over previous
//
#include <hip/hip_runtime.h>

#define NCLS   100000
#define FEAT   192
#define F4     48
#define TILE   64
#define NT     ((NCLS + TILE - 1)/TILE)   // 1563

// workspace layout (float offsets)
#define XN_OFF   0
#define CM_OFF   6144
#define SM_OFF   6176
#define TH_OFF   6208
#define MM_OFF   6240
#define RG_OFF   6272
#define LV_OFF   6304
#define TGT_OFF  6336      // tgt2[s][m], log2-domain (written by k2 hit-path)
#define CMAT_OFF 7360
#define PART_OFF 8384

#define L2E30 43.2808512266689f
#define LN2   0.69314718055994531f

__device__ __forceinline__ float dot4(float4 a, float4 b){
  return fmaf(a.x,b.x, fmaf(a.y,b.y, fmaf(a.z,b.z, a.w*b.w)));
}
__device__ __forceinline__ void fma4(float4& a, float4 x, float4 w){
  a.x = fmaf(x.x,w.x,a.x); a.y = fmaf(x.y,w.y,a.y);
  a.z = fmaf(x.z,w.z,a.z); a.w = fmaf(x.w,w.w,a.w);
}
__device__ __forceinline__ float hsum4(float4 v){ return (v.x+v.y)+(v.z+v.w); }

// ---------------- K1: prep (xn, per-m params, lv) ----------------
__global__ __launch_bounds__(256) void k1_prep(const float* __restrict__ pe,
                                               const int* __restrict__ gt,
                                               float* __restrict__ ws)
{
  __shared__ float4 PE4[1536];
  __shared__ float INVN[32];
  const int tid = threadIdx.x;
  const float4* pe4 = (const float4*)pe;
  for (int i = tid; i < 1536; i += 256) PE4[i] = pe4[i];
  __syncthreads();

  const int m   = tid >> 3;
  const int sub = tid & 7;
  float ssq = 0.f;
  for (int j = 0; j < 6; ++j){ float4 v = PE4[m*F4 + sub + 8*j]; ssq += dot4(v,v); }
  ssq += __shfl_xor(ssq,1); ssq += __shfl_xor(ssq,2); ssq += __shfl_xor(ssq,4);
  float nrm = sqrtf(ssq);
  if (sub == 0){
    INVN[m] = 1.f / fmaxf(nrm, 1e-12f);
    float nc = fminf(fmaxf(nrm, 10.f), 110.f);
    float mi = fmaf(0.01f, nc, 100.f/nc);
    const float pi = 3.14159265358979323846f;
    ws[CM_OFF+m] = cosf(mi);
    ws[SM_OFF+m] = sinf(mi);
    ws[TH_OFF+m] = cosf(pi - mi);
    ws[MM_OFF+m] = sinf(pi - mi)*mi;
    float dr = nc - 60.f;
    ws[RG_OFF+m] = 0.07f*dr*dr;              // GAMMA*LMBDA*0.01 = 0.07
  }
  if (tid < 32) ws[LV_OFF+tid] = (float)gt[tid];
  __syncthreads();

  for (int i = tid; i < 6144; i += 256)
    ws[XN_OFF+i] = ((float*)PE4)[i] * INVN[i/FEAT];
}

// ---------------- K2: fused GEMM + online logsumexp ----------------
// lane <-> class (64/tile), wave w <-> m-group [8w,8w+8).
// W read directly from global (vmcnt, unroll-8 ILP); xn via scalar loads
// (lgkmcnt = SMEM only -> precise waits). LDS only for the (ob,os)
// redistribution (16.5KB) -> 4 blocks/CU.
__global__ __launch_bounds__(256, 4) void k2_main(const float* __restrict__ wgt,
                                                  const float* __restrict__ wsr,
                                                  const int* __restrict__ gt,
                                                  float2* __restrict__ part,
                                                  float* __restrict__ wsw,
                                                  int nb)
{
  __shared__ float4 OBS[TILE*8];   // 8KB, group slot g' = g ^ (row&7)
  __shared__ float4 OSS[TILE*8];   // 8KB

  const int tid  = threadIdx.x;
  const int lane = tid & 63;
  const int wv   = tid >> 6;
  const int m0   = __builtin_amdgcn_readfirstlane(wv*8);
  const float4* gw4 = (const float4*)wgt;
  const float4* xn4 = (const float4*)(wsr + XN_OFF);

  float cmv[8], smv[8], thw[8], mmw[8];   // wave-uniform -> SGPRs
#pragma unroll
  for (int q = 0; q < 8; ++q){
    cmv[q] = wsr[CM_OFF+m0+q]; smv[q] = wsr[SM_OFF+m0+q];
    thw[q] = wsr[TH_OFF+m0+q]; mmw[q] = wsr[MM_OFF+m0+q];
  }

  const int s_acc = tid & 31;
  const int mgr   = tid >> 5;
  const int gt_s  = gt[s_acc];
  const float lvs = (float)gt_s;
  float mx[4], sums[4];
#pragma unroll
  for (int qi = 0; qi < 4; ++qi){ mx[qi] = -1e30f; sums[qi] = 0.f; }

#define ACC_BODY(ci)                                                        \
  {                                                                         \
    int slot = (ci)*8 + (mgr ^ ((ci) & 7));                                 \
    float4 ob = OBS[slot];                                                  \
    float4 os = OSS[slot];                                                  \
    float ov[4] = { fmaf(lvs, os.x, ob.x), fmaf(lvs, os.y, ob.y),           \
                    fmaf(lvs, os.z, ob.z), fmaf(lvs, os.w, ob.w) };         \
    _Pragma("unroll")                                                       \
    for (int qi = 0; qi < 4; ++qi){                                         \
      float d2 = ov[qi] - mx[qi];                                           \
      float e2 = exp2f(-fabsf(d2));                                         \
      if (d2 > 0.f){ sums[qi] = fmaf(sums[qi], e2, 1.f); mx[qi] = ov[qi]; } \
      else if (d2 > -28.f) sums[qi] += e2;                                  \
    }                                                                       \
  }

  for (int t = blockIdx.x; t < NT; t += nb){
    const int c0 = t*TILE;
    const int nv = (NCLS - c0 < TILE) ? (NCLS - c0) : TILE;
    const int cls = (lane < nv) ? lane : (nv-1);
    const float4* wrow = gw4 + (long)(c0 + cls)*F4;

    // ---- dot: acc[q] = sum_k xn[m0+q][k]*W[cls][k]; each lane its own |W|^2
    float4 acc[8]; float4 nsq = make_float4(0,0,0,0);
#pragma unroll
    for (int q = 0; q < 8; ++q) acc[q] = make_float4(0,0,0,0);
#pragma unroll 8
    for (int k4 = 0; k4 < F4; ++k4){
      float4 w = wrow[k4];
      fma4(nsq, w, w);
#pragma unroll
      for (int q = 0; q < 8; ++q){
        int xi = __builtin_amdgcn_readfirstlane((m0 + q)*F4 + k4);
        fma4(acc[q], xn4[xi], w);
      }
    }
    // ---- transform: cosine -> (ob, os) in log2 domain
    float invn = rsqrtf(fmaxf(hsum4(nsq), 1e-24f));
    float4 obv[2], osv[2];
#pragma unroll
    for (int q = 0; q < 8; ++q){
      float c = hsum4(acc[q]) * invn;
      float sine = sqrtf(fminf(fmaxf(1.f - c*c, 0.f), 1.f));
      float phi = c*cmv[q] - sine*smv[q];
      phi = (c > thw[q]) ? phi : (c - mmw[q]);
      ((float*)&obv[q>>2])[q&3] = L2E30 * c;
      ((float*)&osv[q>>2])[q&3] = L2E30 * (phi - c);
    }
    __syncthreads();                     // barA: prev accumulate done reading
    {
      const int k7 = lane & 7;
      OBS[lane*8 + ((2*wv)   ^ k7)] = obv[0];
      OBS[lane*8 + ((2*wv+1) ^ k7)] = obv[1];
      OSS[lane*8 + ((2*wv)   ^ k7)] = osv[0];
      OSS[lane*8 + ((2*wv+1) ^ k7)] = osv[1];
    }
    __syncthreads();                     // barB: OBS/OSS visible
    // ---- rare tgt-hit: record tgt2[s][m]
    {
      int rel = gt_s - c0;
      if ((unsigned)rel < (unsigned)nv){
        int slot = rel*8 + (mgr ^ (rel & 7));
        float4 ob = OBS[slot];
        float4 os = OSS[slot];
        wsw[TGT_OFF + s_acc*32 + 4*mgr + 0] = fmaf(lvs, os.x, ob.x);
        wsw[TGT_OFF + s_acc*32 + 4*mgr + 1] = fmaf(lvs, os.y, ob.y);
        wsw[TGT_OFF + s_acc*32 + 4*mgr + 2] = fmaf(lvs, os.z, ob.z);
        wsw[TGT_OFF + s_acc*32 + 4*mgr + 3] = fmaf(lvs, os.w, ob.w);
      }
    }
    // ---- accumulate: online lse over this tile's classes
    if (nv == TILE){
#pragma unroll 8
      for (int ci = 0; ci < TILE; ++ci) ACC_BODY(ci)
    } else {
      for (int ci = 0; ci < nv; ++ci) ACC_BODY(ci)
    }
  }
#undef ACC_BODY
#pragma unroll
  for (int qi = 0; qi < 4; ++qi){
    int pp = s_acc*32 + 4*mgr + qi;
    part[(long)pp*nb + blockIdx.x] = make_float2(mx[qi], sums[qi]);
  }
}

// ---------------- K3: combine partials -> cost matrix ----------------
__global__ __launch_bounds__(64) void k3_reduce(const float2* part, float* ws, int nb)
{
  const int p = blockIdx.x;
  const int l = threadIdx.x;
  float M = -1e30f, S = 0.f;
  for (int base = l; base < nb; base += 64){
    float2 v = part[(long)p*nb + base];
    float M2 = fmaxf(M, v.x);
    S = S*exp2f(M - M2) + v.y*exp2f(v.x - M2);
    M = M2;
  }
  for (int k = 1; k < 64; k <<= 1){
    float Mo = __shfl_xor(M, k);
    float So = __shfl_xor(S, k);
    float M2 = fmaxf(M, Mo);
    S = S*exp2f(M - M2) + So*exp2f(Mo - M2);
    M = M2;
  }
  if (l == 0){
    float lse2 = M + log2f(S);
    ws[CMAT_OFF + p] = LN2*(lse2 - ws[TGT_OFF + p]) + ws[RG_OFF + (p & 31)];
  }
}

// ---------------- K4: Hungarian (32-lane DPP ladder + pipelined row fetch) ----------------
__device__ __forceinline__ float wave_min32(float x){
  float r = x;
#define DPPSTEP(ctrl) { int t_ = __builtin_amdgcn_update_dpp(__float_as_int(r), __float_as_int(r), (ctrl), 0xf, 0xf, false); r = fminf(r, __int_as_float(t_)); }
  DPPSTEP(0x111)  // row_shr:1
  DPPSTEP(0x112)  // row_shr:2
  DPPSTEP(0x114)  // row_shr:4
  DPPSTEP(0x118)  // row_shr:8
  DPPSTEP(0x142)  // row_bcast:15
#undef DPPSTEP
  return __int_as_float(__builtin_amdgcn_readlane(__float_as_int(r), 31));
}

__global__ __launch_bounds__(64) void k4_final(const float* __restrict__ psin,
                                               const float* __restrict__ wsr,
                                               float* __restrict__ out)
{
  __shared__ float CL[1024];
  const int l = threadIdx.x;
  for (int i = l; i < 1024; i += 64) CL[i] = wsr[CMAT_OFF + i];
  __syncthreads();

  float v = 0.f, uu = 0.f;     // v[j], u[p[j]] for lane's column j = l+1
  int p = 0, way = 0;
  for (int i = 1; i <= 32; ++i){
    float minv = 1e30f;
    int used = (l < 32) ? 0 : 1;
    way = 0;
    float uu0 = 0.f;
    int j0 = 0;
    float u0 = 0.f;
    float cst = CL[(i-1)*32 + (l & 31)];        // preload row i
    for (int guard = 0; guard < 64; ++guard){
      float cur = cst - u0 - v;
      if (!used && cur < minv){ minv = cur; way = j0; }
      float mval = used ? 1e30f : minv;
      float dmin = wave_min32(mval);
      unsigned long long b = __ballot(mval == dmin);
      int j1 = __builtin_ctzll(b) + 1;          // lowest j argmin = ref tie-break
      int pn = __builtin_amdgcn_readlane(p, j1-1);
      int i0n = (pn > 0) ? pn : 1;
      float cstn = CL[(i0n-1)*32 + (l & 31)];   // prefetch next row early
      if (used){ uu += dmin; v -= dmin; } else { minv -= dmin; }
      uu0 += dmin;
      j0 = j1;
      if (pn == 0) break;
      if (l == j1-1) used = 1;                  // mark j1 used for next iter
      u0 = __int_as_float(__builtin_amdgcn_readlane(__float_as_int(uu), j1-1));
      cst = cstn;
    }
    // augment along 'way' chain
    for (int guard = 0; guard < 40 && j0 != 0; ++guard){
      int jw = __builtin_amdgcn_readlane(way, j0-1);
      int pp_; float pu;
      if (jw == 0){ pp_ = i; pu = uu0; }
      else {
        pp_ = __builtin_amdgcn_readlane(p, jw-1);
        pu = __int_as_float(__builtin_amdgcn_readlane(__float_as_int(uu), jw-1));
      }
      if (l == j0-1){ p = pp_; uu = pu; }
      j0 = jw;
    }
  }
  float csum = 0.f;
  if (l < 32) csum = CL[(p-1)*32 + l];
  for (int k = 1; k < 64; k <<= 1) csum += __shfl_xor(csum, k);
  float lex = 0.f;
  if (l < 32){
    float pv = psin[l];
    pv = fminf(fmaxf(pv, 1e-6f), 1.f - 1e-6f);
    lex = -logf(pv);
  }
  for (int k = 1; k < 64; k <<= 1) lex += __shfl_xor(lex, k);
  if (l == 0)
    out[0] = csum/32.f + 100.f*(lex/32.f) + 100.f*LN2;
}

extern "C" void kernel_launch(void* const* d_in, const int* in_sizes, int n_in,
                              void* d_out, int out_size, void* d_ws, size_t ws_size,
                              hipStream_t stream)
{
  (void)in_sizes; (void)n_in; (void)out_size;
  const float* pe  = (const float*)d_in[0];
  const float* ps  = (const float*)d_in[1];
  const int*   gt  = (const int*)  d_in[2];
  const float* wgt = (const float*)d_in[3];
  float* ws  = (float*)d_ws;
  float* out = (float*)d_out;
  // part needs (PART_OFF + 1024*nb*2) floats; pick nb by available workspace
  const int nb = (ws_size >= (size_t)(PART_OFF + 2u*1024u*1024u)*4u) ? 1024 : 512;
  hipLaunchKernelGGL(k1_prep,   dim3(1),    dim3(256), 0, stream, pe, gt, ws);
  hipLaunchKernelGGL(k2_main,   dim3(nb),   dim3(256), 0, stream, wgt, ws, gt,
                     (float2*)(ws + PART_OFF), ws, nb);
  hipLaunchKernelGGL(k3_reduce, dim3(1024), dim3(64),  0, stream,
                     (const float2*)(ws + PART_OFF), ws, nb);
  hipLaunchKernelGGL(k4_final,  dim3(1),    dim3(64),  0, stream, ps, ws, out);
}